// Round 12
// baseline (1290.909 us; speedup 1.0000x reference)
//
#include <hip/hip_runtime.h>
#include <math.h>

#define NGRAPH 128
#define NPER   512
#define EPER   8192
#define NFEAT  4
#define NREL   5
#define DD     128
#define MAXNB  50
#define MAXW   21
#define NCLS   5

typedef unsigned short ushortT;
typedef unsigned char ucharT;

// ===================== Kernel A: build sorted in/out CSRs (proven r3-r11) =====================
#define NTA 1024

__device__ __forceinline__ void scanExcl(const int* cnt, int* offs, int* tA,
                                         int* tB, int tid) {
  if (tid < NPER) tA[tid] = cnt[tid];
  __syncthreads();
  int* a = tA; int* b = tB;
  for (int d = 1; d < NPER; d <<= 1) {
    if (tid < NPER) {
      int v = a[tid];
      if (tid >= d) v += a[tid - d];
      b[tid] = v;
    }
    __syncthreads();
    int* t = a; a = b; b = t;
  }
  if (tid < NPER) offs[tid] = a[tid] - cnt[tid];
  __syncthreads();
}

__global__ __launch_bounds__(NTA, 1)
void build_csr2(const int* __restrict__ esrc, const int* __restrict__ edst,
                const int* __restrict__ etype, const float* __restrict__ x,
                ushortT* __restrict__ gBin, ushortT* __restrict__ gOut,
                int* __restrict__ pIn, int* __restrict__ pOut,
                int* __restrict__ gSE) {
  __shared__ int keyS[EPER];
  __shared__ int auxS[EPER];
  __shared__ ushortT nodS[EPER];
  __shared__ ucharT etyS[EPER];
  __shared__ int cnt[NPER], offs[NPER], fill[NPER];
  __shared__ int se[2];
  const int bid = blockIdx.x, tid = threadIdx.x;
  const int half = bid >> 7;             // 0: in-CSR, 1: out-CSR
  const int g = bid & 127;
  const int nbase = g * NPER, ebase = g * EPER;

  if (tid < NPER) { cnt[tid] = 0; fill[tid] = 0; }
  if (tid < 2) se[tid] = NPER;
  __syncthreads();

  if (half == 0) {
    for (int e = tid; e < EPER; e += NTA) {
      auxS[e] = esrc[ebase + e] - nbase;
      etyS[e] = (ucharT)etype[ebase + e];
      int d = edst[ebase + e] - nbase;
      atomicAdd(&cnt[d], 1);
    }
    __syncthreads();
    scanExcl(cnt, offs, keyS, keyS + NPER, tid);
    for (int e = tid; e < EPER; e += NTA) {
      int d = edst[ebase + e] - nbase;
      int pos = offs[d] + atomicAdd(&fill[d], 1);
      keyS[pos] = (d << 13) | e;
    }
    __syncthreads();
    for (int p = tid; p < EPER; p += NTA) {
      const int k = keyS[p];
      const int n = k >> 13;
      const int o = offs[n], c = cnt[n];
      int r = 0;
      for (int i = 0; i < c; ++i) r += (keyS[o + i] < k);
      const int e = k & (EPER - 1);
      gBin[(size_t)g * EPER + o + r] = (ushortT)((auxS[e] << 3) | (int)etyS[e]);
    }
    if (tid < NPER) pIn[nbase + tid] = (offs[tid] << 14) | cnt[tid];
  } else {
    for (int e = tid; e < EPER; e += NTA) {
      int s = esrc[ebase + e] - nbase;
      auxS[e] = s;
      atomicAdd(&cnt[s], 1);
    }
    if (tid < NPER) {
      if (x[(size_t)(nbase + tid) * NFEAT + 0] > 0.5f) atomicMin(&se[0], tid);
      if (x[(size_t)(nbase + tid) * NFEAT + 1] > 0.5f) atomicMin(&se[1], tid);
    }
    __syncthreads();
    scanExcl(cnt, offs, keyS, keyS + NPER, tid);
    for (int e = tid; e < EPER; e += NTA) {
      int s = auxS[e];
      int d = edst[ebase + e] - nbase;
      int pos = offs[s] + atomicAdd(&fill[s], 1);
      keyS[pos] = (d << 13) | e;
      nodS[pos] = (ushortT)s;
    }
    __syncthreads();
    for (int p = tid; p < EPER; p += NTA) {
      const int k = keyS[p];
      const int n = (int)nodS[p];
      const int o = offs[n], c = cnt[n];
      int r = 0;
      for (int i = 0; i < c; ++i) r += (keyS[o + i] < k);
      gOut[(size_t)g * EPER + o + r] = (ushortT)(k >> 13);
    }
    if (tid < NPER) pOut[nbase + tid] = (offs[tid] << 14) | cnt[tid];
    if (tid < 2) gSE[g * 2 + tid] = (se[tid] >= NPER) ? 0 : se[tid];
  }
}

// ===================== Kernel B: RGCN layer, parameterized NPB; XCD-paired =====================
// NPB=256: exact r10/r11 proven shape. NPB=128: half LDS -> 2 blocks/CU.
// Gather inner loop byte-identical; FMA order per output identical -> bit-exact.
template <int FIN, int NPB>
__global__ __launch_bounds__(512, 1)
void rgcn_layer3x(const float* __restrict__ x, float* __restrict__ cs,
                  const ushortT* __restrict__ gBin, const int* __restrict__ pIn,
                  const float* __restrict__ bas, const float* __restrict__ cmp,
                  const float* __restrict__ rt, const float* __restrict__ bi,
                  int l) {
  constexpr int NK4 = (3 * FIN) / 4;
  constexpr int LPN = FIN / 4;
  __shared__ float A_s[NK4 * NPB * 4];
  __shared__ float Bt_s[NK4 * 32 * 4];
  __shared__ float compS[NREL * 2];
  const int bid = blockIdx.x, tid = threadIdx.x;
  const int g = bid & 127, sub = bid >> 7;   // XCD-paired: all subs of g on XCD g%8
  const int nbase = g * NPER;
  const int nb2 = nbase + sub * NPB;

  for (int idx = tid; idx < NK4 * 128; idx += 512) {
    const int k4 = idx >> 7, rem = idx & 127;
    const int o = rem >> 2, c = rem & 3;
    const int k = k4 * 4 + c;
    float v;
    if (k < 2 * FIN) v = bas[k * 32 + o];
    else v = rt[(k - 2 * FIN) * 32 + o];
    Bt_s[(k4 * 32 + o) * 4 + c] = v;
  }
  if (tid < NREL * 2) compS[tid] = cmp[tid];
  for (int idx = tid; idx < NPB * LPN; idx += 512) {
    const int n = idx / LPN, kq = idx % LPN;
    float4 hv;
    if constexpr (FIN == 4)
      hv = *(const float4*)(x + (size_t)(nb2 + n) * NFEAT);
    else
      hv = *(const float4*)(cs + (size_t)(nb2 + n) * DD + (l - 1) * 32 + kq * 4);
    *(float4*)&A_s[((2 * LPN + kq) * NPB + n) * 4] = hv;
  }
  __syncthreads();

  // gather with 2-deep pipeline; code identical to proven r8/r10/r11
  for (int t = tid; t < NPB * LPN; t += 512) {
    const int n = t / LPN, q = t % LPN;
    const int pk = pIn[nb2 + n];
    const int off = pk >> 14, c = pk & 16383;
    const float inv = 1.0f / (float)(c > 1 ? c : 1);
    float4 s0 = make_float4(0.f, 0.f, 0.f, 0.f);
    float4 s1 = make_float4(0.f, 0.f, 0.f, 0.f);
    const ushortT* el = gBin + (size_t)g * EPER + off;
    const float* hb;
    if constexpr (FIN == 4) hb = x + (size_t)nbase * NFEAT;
    else hb = cs + (size_t)nbase * DD + (l - 1) * 32 + q * 4;
    constexpr int STRIDE = (FIN == 4) ? NFEAT : DD;
    if (c > 0) {
      int pe = (int)el[0];
      float4 hv = *(const float4*)(hb + (size_t)(pe >> 3) * STRIDE);
      for (int i = 0; i + 1 < c; ++i) {
        const int pe_n = (int)el[i + 1];
        const float4 hv_n = *(const float4*)(hb + (size_t)(pe_n >> 3) * STRIDE);
        const float c0 = compS[(pe & 7) * 2], c1 = compS[(pe & 7) * 2 + 1];
        s0.x = fmaf(c0, hv.x, s0.x); s0.y = fmaf(c0, hv.y, s0.y);
        s0.z = fmaf(c0, hv.z, s0.z); s0.w = fmaf(c0, hv.w, s0.w);
        s1.x = fmaf(c1, hv.x, s1.x); s1.y = fmaf(c1, hv.y, s1.y);
        s1.z = fmaf(c1, hv.z, s1.z); s1.w = fmaf(c1, hv.w, s1.w);
        pe = pe_n; hv = hv_n;
      }
      const float c0 = compS[(pe & 7) * 2], c1 = compS[(pe & 7) * 2 + 1];
      s0.x = fmaf(c0, hv.x, s0.x); s0.y = fmaf(c0, hv.y, s0.y);
      s0.z = fmaf(c0, hv.z, s0.z); s0.w = fmaf(c0, hv.w, s0.w);
      s1.x = fmaf(c1, hv.x, s1.x); s1.y = fmaf(c1, hv.y, s1.y);
      s1.z = fmaf(c1, hv.z, s1.z); s1.w = fmaf(c1, hv.w, s1.w);
    }
    s0.x *= inv; s0.y *= inv; s0.z *= inv; s0.w *= inv;
    s1.x *= inv; s1.y *= inv; s1.z *= inv; s1.w *= inv;
    *(float4*)&A_s[(q * NPB + n) * 4] = s0;
    *(float4*)&A_s[((LPN + q) * NPB + n) * 4] = s1;
  }
  __syncthreads();

  if constexpr (NPB == 256) {
    // proven r10/r11 tile: 2 nodes x 8 outs
    const int ot = (tid >> 4) & 3;
    const int nt = (tid & 15) | ((tid >> 6) << 4);
    const int n0 = 2 * nt, o0 = 8 * ot;
    float acc[2][8];
#pragma unroll
    for (int i = 0; i < 2; ++i)
#pragma unroll
      for (int j = 0; j < 8; ++j) acc[i][j] = 0.f;
    for (int k4 = 0; k4 < NK4; ++k4) {
      const float4 a0 = *(const float4*)&A_s[(k4 * NPB + n0) * 4];
      const float4 a1 = *(const float4*)&A_s[(k4 * NPB + n0 + 1) * 4];
#pragma unroll
      for (int j = 0; j < 8; ++j) {
        const float4 b = *(const float4*)&Bt_s[(k4 * 32 + o0 + j) * 4];
        acc[0][j] = fmaf(a0.x, b.x, acc[0][j]);
        acc[0][j] = fmaf(a0.y, b.y, acc[0][j]);
        acc[0][j] = fmaf(a0.z, b.z, acc[0][j]);
        acc[0][j] = fmaf(a0.w, b.w, acc[0][j]);
        acc[1][j] = fmaf(a1.x, b.x, acc[1][j]);
        acc[1][j] = fmaf(a1.y, b.y, acc[1][j]);
        acc[1][j] = fmaf(a1.z, b.z, acc[1][j]);
        acc[1][j] = fmaf(a1.w, b.w, acc[1][j]);
      }
    }
#pragma unroll
    for (int i = 0; i < 2; ++i) {
      float4 w0, w1;
      w0.x = tanhf(acc[i][0] + bi[o0 + 0]); w0.y = tanhf(acc[i][1] + bi[o0 + 1]);
      w0.z = tanhf(acc[i][2] + bi[o0 + 2]); w0.w = tanhf(acc[i][3] + bi[o0 + 3]);
      w1.x = tanhf(acc[i][4] + bi[o0 + 4]); w1.y = tanhf(acc[i][5] + bi[o0 + 5]);
      w1.z = tanhf(acc[i][6] + bi[o0 + 6]); w1.w = tanhf(acc[i][7] + bi[o0 + 7]);
      float* dst = cs + (size_t)(nb2 + n0 + i) * DD + l * 32 + o0;
      *(float4*)dst = w0;
      *(float4*)(dst + 4) = w1;
    }
  } else {
    // NPB=128 tile: 1 node x 8 outs (same k-ascending x,y,z,w order -> bit-exact)
    const int ot = tid >> 7;           // 0..3
    const int n0 = tid & 127;
    const int o0 = 8 * ot;
    float acc[8];
#pragma unroll
    for (int j = 0; j < 8; ++j) acc[j] = 0.f;
    for (int k4 = 0; k4 < NK4; ++k4) {
      const float4 a0 = *(const float4*)&A_s[(k4 * NPB + n0) * 4];
#pragma unroll
      for (int j = 0; j < 8; ++j) {
        const float4 b = *(const float4*)&Bt_s[(k4 * 32 + o0 + j) * 4];
        acc[j] = fmaf(a0.x, b.x, acc[j]);
        acc[j] = fmaf(a0.y, b.y, acc[j]);
        acc[j] = fmaf(a0.z, b.z, acc[j]);
        acc[j] = fmaf(a0.w, b.w, acc[j]);
      }
    }
    float4 w0, w1;
    w0.x = tanhf(acc[0] + bi[o0 + 0]); w0.y = tanhf(acc[1] + bi[o0 + 1]);
    w0.z = tanhf(acc[2] + bi[o0 + 2]); w0.w = tanhf(acc[3] + bi[o0 + 3]);
    w1.x = tanhf(acc[4] + bi[o0 + 4]); w1.y = tanhf(acc[5] + bi[o0 + 5]);
    w1.z = tanhf(acc[6] + bi[o0 + 6]); w1.w = tanhf(acc[7] + bi[o0 + 7]);
    float* dst = cs + (size_t)(nb2 + n0) * DD + l * 32 + o0;
    *(float4*)dst = w0;
    *(float4*)(dst + 4) = w1;
  }
}

// ===================== Kernel P: P[n][j] = W[j]. cs_row(n)  (verbatim r11) =====================
__global__ __launch_bounds__(256, 1)
void p_gemm(const float* __restrict__ cs, const float* __restrict__ walk_w,
            float* __restrict__ P) {
  __shared__ float A_s[32 * 128 * 4];
  __shared__ float BtS[32 * 64 * 4];
  const int bid = blockIdx.x, tid = threadIdx.x;
  const int g = bid & 127, quad = bid >> 7;
  const int nb2 = g * NPER + quad * 128;

  for (int idx = tid; idx < 64 * 32; idx += 256) {
    const int j = idx >> 5, k4 = idx & 31;
    float4 v = make_float4(0.f, 0.f, 0.f, 0.f);
    if (j < MAXNB) v = *(const float4*)(walk_w + j * DD + k4 * 4);
    *(float4*)&BtS[(k4 * 64 + j) * 4] = v;
  }
  for (int idx = tid; idx < 128 * 32; idx += 256) {
    const int n = idx >> 5, k4 = idx & 31;
    const float4 v = *(const float4*)(cs + (size_t)(nb2 + n) * DD + k4 * 4);
    *(float4*)&A_s[(k4 * 128 + n) * 4] = v;
  }
  __syncthreads();

  const int nt = tid & 31, jt = tid >> 5;
  const int n0 = 4 * nt, j0 = 8 * jt;
  float acc[4][8];
#pragma unroll
  for (int i = 0; i < 4; ++i)
#pragma unroll
    for (int j = 0; j < 8; ++j) acc[i][j] = 0.f;
  for (int k4 = 0; k4 < 32; ++k4) {
    const float4 a0 = *(const float4*)&A_s[(k4 * 128 + n0 + 0) * 4];
    const float4 a1 = *(const float4*)&A_s[(k4 * 128 + n0 + 1) * 4];
    const float4 a2 = *(const float4*)&A_s[(k4 * 128 + n0 + 2) * 4];
    const float4 a3 = *(const float4*)&A_s[(k4 * 128 + n0 + 3) * 4];
#pragma unroll
    for (int j = 0; j < 8; ++j) {
      const float4 b = *(const float4*)&BtS[(k4 * 64 + j0 + j) * 4];
      acc[0][j] = fmaf(a0.x, b.x, acc[0][j]); acc[0][j] = fmaf(a0.y, b.y, acc[0][j]);
      acc[0][j] = fmaf(a0.z, b.z, acc[0][j]); acc[0][j] = fmaf(a0.w, b.w, acc[0][j]);
      acc[1][j] = fmaf(a1.x, b.x, acc[1][j]); acc[1][j] = fmaf(a1.y, b.y, acc[1][j]);
      acc[1][j] = fmaf(a1.z, b.z, acc[1][j]); acc[1][j] = fmaf(a1.w, b.w, acc[1][j]);
      acc[2][j] = fmaf(a2.x, b.x, acc[2][j]); acc[2][j] = fmaf(a2.y, b.y, acc[2][j]);
      acc[2][j] = fmaf(a2.z, b.z, acc[2][j]); acc[2][j] = fmaf(a2.w, b.w, acc[2][j]);
      acc[3][j] = fmaf(a3.x, b.x, acc[3][j]); acc[3][j] = fmaf(a3.y, b.y, acc[3][j]);
      acc[3][j] = fmaf(a3.z, b.z, acc[3][j]); acc[3][j] = fmaf(a3.w, b.w, acc[3][j]);
    }
  }
#pragma unroll
  for (int i = 0; i < 4; ++i) {
    float4 w0, w1;
    w0.x = acc[i][0]; w0.y = acc[i][1]; w0.z = acc[i][2]; w0.w = acc[i][3];
    w1.x = acc[i][4]; w1.y = acc[i][5]; w1.z = acc[i][6]; w1.w = acc[i][7];
    float* dst = P + (size_t)(nb2 + n0 + i) * 64 + j0;
    *(float4*)dst = w0;
    *(float4*)(dst + 4) = w1;
  }
}

// ===================== Kernel C: P-based walk + MLP head (verbatim r11) =====================
__global__ __launch_bounds__(256, 1)
void walk_head5(const float* __restrict__ cs, const float* __restrict__ P,
                const ushortT* __restrict__ gOut, const int* __restrict__ pOut,
                const int* __restrict__ gSE, const float* __restrict__ walk_b,
                const float* __restrict__ lin1_w, const float* __restrict__ lin1_b,
                const float* __restrict__ lin2_w, const float* __restrict__ lin2_b,
                float* __restrict__ out) {
  __shared__ ushortT gOutS[EPER];
  __shared__ int pOutS[NPER];
  __shared__ int travS[NPER];
  __shared__ int listS[MAXW + 2];
  __shared__ int scal[4];
  __shared__ float pooledS[DD], hidS[DD], logitsS[8];
  const int g = blockIdx.x, tid = threadIdx.x;
  const int nbase = g * NPER;
  const float* Pg = P + (size_t)nbase * 64;

  {
    const unsigned int* g32 = (const unsigned int*)(gOut + (size_t)g * EPER);
    unsigned int* s32 = (unsigned int*)gOutS;
    for (int i = tid; i < EPER / 2; i += 256) s32[i] = g32[i];
    for (int i = tid; i < NPER; i += 256) {
      pOutS[i] = pOut[nbase + i];
      travS[i] = 0;
    }
  }
  const int startN = gSE[2 * g];
  const int endN = gSE[2 * g + 1];
  if (tid == 0) { travS[startN] = 1; listS[0] = startN; }
  __syncthreads();

  if (tid < 64) {
    const int j = tid;
    float l = 0.f;
    if (j < MAXNB) l = Pg[(size_t)startN * 64 + j] + walk_b[j];
    int node = startN, visited = 1, nrows = 1;
    for (int step = 0; step < MAXW; ++step) {
      const int pk = pOutS[node];
      const int off = pk >> 14, c = pk & 16383;
      const int jm = (c < MAXNB) ? c : MAXNB;
      float myval = -INFINITY;
      if (j < jm) {
        const int nb = (int)gOutS[off + j];
        if (!travS[nb]) myval = l;
      }
      int myidx = j;
#pragma unroll
      for (int o = 1; o < 64; o <<= 1) {
        const float ov = __shfl_xor(myval, o, 64);
        const int oi = __shfl_xor(myidx, o, 64);
        if (ov > myval || (ov == myval && oi < myidx)) { myval = ov; myidx = oi; }
      }
      const bool no_nbr = (c == 0);
      const int sel = no_nbr ? 0 : (int)gOutS[off + myidx];
      const int tgt = no_nbr ? endN : sel;
      if (j == 0) listS[nrows] = tgt;
      nrows++;
      if (j < MAXNB) l += Pg[(size_t)tgt * 64 + j];
      if (!no_nbr) {
        if (j == 0) travS[sel] = 1;
        visited++;
        node = sel;
      }
      if (no_nbr || sel == endN) break;
    }
    if (j == 0) { scal[0] = nrows; scal[1] = visited; }
  }
  __syncthreads();

  const int nrows = scal[0];
  if (tid < DD) {
    float acc = cs[(size_t)(nbase + listS[0]) * DD + tid];
    for (int t = 1; t < nrows; ++t)
      acc += cs[(size_t)(nbase + listS[t]) * DD + tid];
    pooledS[tid] = acc / (float)scal[1];
  }
  __syncthreads();
  if (tid < DD) {
    const float4* w4 = (const float4*)(lin1_w + (size_t)tid * DD);
    float s = lin1_b[tid];
#pragma unroll 8
    for (int k4 = 0; k4 < DD / 4; ++k4) {
      const float4 wv = w4[k4];
      s += wv.x * pooledS[k4 * 4 + 0] + wv.y * pooledS[k4 * 4 + 1]
         + wv.z * pooledS[k4 * 4 + 2] + wv.w * pooledS[k4 * 4 + 3];
    }
    hidS[tid] = fmaxf(s, 0.f);
  }
  __syncthreads();
  if (tid < NCLS) {
    const float4* w4 = (const float4*)(lin2_w + (size_t)tid * DD);
    float s = lin2_b[tid];
#pragma unroll 8
    for (int k4 = 0; k4 < DD / 4; ++k4) {
      const float4 wv = w4[k4];
      s += wv.x * hidS[k4 * 4 + 0] + wv.y * hidS[k4 * 4 + 1]
         + wv.z * hidS[k4 * 4 + 2] + wv.w * hidS[k4 * 4 + 3];
    }
    logitsS[tid] = s;
  }
  __syncthreads();
  if (tid < NCLS) {
    float m = logitsS[0];
    for (int c = 1; c < NCLS; ++c) m = fmaxf(m, logitsS[c]);
    float sum = 0.f;
    for (int c = 0; c < NCLS; ++c) sum += expf(logitsS[c] - m);
    const float lse = m + logf(sum);
    out[g * NCLS + tid] = logitsS[tid] - lse;
  }
}

// ===================== Fallback walk (verbatim r9-r11, proven) =====================
__global__ __launch_bounds__(256, 1)
void walk_head4(const float* __restrict__ cs, const ushortT* __restrict__ gOut,
                const int* __restrict__ pOut, const int* __restrict__ gSE,
                const float* __restrict__ walk_w, const float* __restrict__ walk_b,
                const float* __restrict__ lin1_w, const float* __restrict__ lin1_b,
                const float* __restrict__ lin2_w, const float* __restrict__ lin2_b,
                float* __restrict__ out) {
  __shared__ float wT2[64 * 136];
  __shared__ float rowS[DD];
  __shared__ ushortT gOutS[EPER];
  __shared__ int pOutS[NPER];
  __shared__ int travS[NPER];
  __shared__ int listS[MAXW + 2];
  __shared__ int scal[4];
  __shared__ float pooledS[DD], hidS[DD], logitsS[8];
  const int g = blockIdx.x, tid = threadIdx.x;
  const int nbase = g * NPER;

  for (int i = tid; i < 64 * 128; i += 256) {
    const int j = i >> 7, k = i & 127;
    wT2[j * 136 + k] = (j < MAXNB) ? walk_w[j * DD + k] : 0.f;
  }
  {
    const unsigned int* g32 = (const unsigned int*)(gOut + (size_t)g * EPER);
    unsigned int* s32 = (unsigned int*)gOutS;
    for (int i = tid; i < EPER / 2; i += 256) s32[i] = g32[i];
    for (int i = tid; i < NPER; i += 256) {
      pOutS[i] = pOut[nbase + i];
      travS[i] = 0;
    }
  }
  const int startN = gSE[2 * g];
  const int endN = gSE[2 * g + 1];
  if (tid < 64)
    ((float2*)rowS)[tid] = ((const float2*)(cs + (size_t)(nbase + startN) * DD))[tid];
  if (tid == 0) { travS[startN] = 1; listS[0] = startN; }
  __syncthreads();

  if (tid < 64) {
    const int j = tid;
    const float* wrow = wT2 + j * 136;
    float l = (j < MAXNB) ? walk_b[j] : 0.f;
#pragma unroll
    for (int k4 = 0; k4 < 32; ++k4) {
      const float4 r = *(const float4*)&rowS[k4 * 4];
      const float4 w = *(const float4*)&wrow[k4 * 4];
      l = fmaf(w.w, r.w, fmaf(w.z, r.z, fmaf(w.y, r.y, fmaf(w.x, r.x, l))));
    }
    int node = startN, visited = 1, nrows = 1;
    for (int step = 0; step < MAXW; ++step) {
      const int pk = pOutS[node];
      const int off = pk >> 14, c = pk & 16383;
      const int jm = (c < MAXNB) ? c : MAXNB;
      float myval = -INFINITY;
      if (j < jm) {
        const int nb = (int)gOutS[off + j];
        if (!travS[nb]) myval = l;
      }
      int myidx = j;
#pragma unroll
      for (int o = 1; o < 64; o <<= 1) {
        const float ov = __shfl_xor(myval, o, 64);
        const int oi = __shfl_xor(myidx, o, 64);
        if (ov > myval || (ov == myval && oi < myidx)) { myval = ov; myidx = oi; }
      }
      const bool no_nbr = (c == 0);
      const int sel = no_nbr ? 0 : (int)gOutS[off + myidx];
      const int tgt = no_nbr ? endN : sel;
      if (j == 0) listS[nrows] = tgt;
      nrows++;
      const float2 rv = ((const float2*)(cs + (size_t)(nbase + tgt) * DD))[j];
      ((float2*)rowS)[j] = rv;
#pragma unroll
      for (int k4 = 0; k4 < 32; ++k4) {
        const float4 r = *(const float4*)&rowS[k4 * 4];
        const float4 w = *(const float4*)&wrow[k4 * 4];
        l = fmaf(w.w, r.w, fmaf(w.z, r.z, fmaf(w.y, r.y, fmaf(w.x, r.x, l))));
      }
      if (!no_nbr) {
        if (j == 0) travS[sel] = 1;
        visited++;
        node = sel;
      }
      if (no_nbr || sel == endN) break;
    }
    if (j == 0) { scal[0] = nrows; scal[1] = visited; }
  }
  __syncthreads();

  const int nrows = scal[0];
  if (tid < DD) {
    float acc = cs[(size_t)(nbase + listS[0]) * DD + tid];
    for (int t = 1; t < nrows; ++t)
      acc += cs[(size_t)(nbase + listS[t]) * DD + tid];
    pooledS[tid] = acc / (float)scal[1];
  }
  __syncthreads();
  if (tid < DD) {
    const float4* w4 = (const float4*)(lin1_w + (size_t)tid * DD);
    float s = lin1_b[tid];
#pragma unroll 8
    for (int k4 = 0; k4 < DD / 4; ++k4) {
      const float4 wv = w4[k4];
      s += wv.x * pooledS[k4 * 4 + 0] + wv.y * pooledS[k4 * 4 + 1]
         + wv.z * pooledS[k4 * 4 + 2] + wv.w * pooledS[k4 * 4 + 3];
    }
    hidS[tid] = fmaxf(s, 0.f);
  }
  __syncthreads();
  if (tid < NCLS) {
    const float4* w4 = (const float4*)(lin2_w + (size_t)tid * DD);
    float s = lin2_b[tid];
#pragma unroll 8
    for (int k4 = 0; k4 < DD / 4; ++k4) {
      const float4 wv = w4[k4];
      s += wv.x * hidS[k4 * 4 + 0] + wv.y * hidS[k4 * 4 + 1]
         + wv.z * hidS[k4 * 4 + 2] + wv.w * hidS[k4 * 4 + 3];
    }
    logitsS[tid] = s;
  }
  __syncthreads();
  if (tid < NCLS) {
    float m = logitsS[0];
    for (int c = 1; c < NCLS; ++c) m = fmaxf(m, logitsS[c]);
    float sum = 0.f;
    for (int c = 0; c < NCLS; ++c) sum += expf(logitsS[c] - m);
    const float lse = m + logf(sum);
    out[g * NCLS + tid] = logitsS[tid] - lse;
  }
}

extern "C" void kernel_launch(void* const* d_in, const int* in_sizes, int n_in,
                              void* d_out, int out_size, void* d_ws, size_t ws_size,
                              hipStream_t stream) {
  const float* x = (const float*)d_in[0];
  const int* ei = (const int*)d_in[1];
  const int E = in_sizes[1] / 2;
  const int* esrc = ei;
  const int* edst = ei + E;
  const int* et = (const int*)d_in[2];

  char* ws = (char*)d_ws;
  float* cs = (float*)ws;
  size_t off = (size_t)NGRAPH * NPER * DD * sizeof(float);
  ushortT* gBin = (ushortT*)(ws + off); off += (size_t)NGRAPH * EPER * sizeof(ushortT);
  ushortT* gOut = (ushortT*)(ws + off); off += (size_t)NGRAPH * EPER * sizeof(ushortT);
  int* pIn = (int*)(ws + off); off += (size_t)NGRAPH * NPER * sizeof(int);
  int* pOut = (int*)(ws + off); off += (size_t)NGRAPH * NPER * sizeof(int);
  int* gSE = (int*)(ws + off); off += (size_t)NGRAPH * 2 * sizeof(int);
  off = (off + 255) & ~(size_t)255;
  float* Pbuf = (float*)(ws + off);
  const size_t pBytes = (size_t)NGRAPH * NPER * 64 * sizeof(float);
  const bool haveP = (ws_size >= off + pBytes);

  build_csr2<<<dim3(2 * NGRAPH), dim3(NTA), 0, stream>>>(esrc, edst, et, x, gBin,
                                                         gOut, pIn, pOut, gSE);
  rgcn_layer3x<NFEAT, 256><<<dim3(2 * NGRAPH), dim3(512), 0, stream>>>(
      x, cs, gBin, pIn, (const float*)d_in[4], (const float*)d_in[5],
      (const float*)d_in[6], (const float*)d_in[7], 0);
  rgcn_layer3x<32, 128><<<dim3(4 * NGRAPH), dim3(512), 0, stream>>>(
      x, cs, gBin, pIn, (const float*)d_in[8], (const float*)d_in[9],
      (const float*)d_in[10], (const float*)d_in[11], 1);
  rgcn_layer3x<32, 128><<<dim3(4 * NGRAPH), dim3(512), 0, stream>>>(
      x, cs, gBin, pIn, (const float*)d_in[12], (const float*)d_in[13],
      (const float*)d_in[14], (const float*)d_in[15], 2);
  rgcn_layer3x<32, 128><<<dim3(4 * NGRAPH), dim3(512), 0, stream>>>(
      x, cs, gBin, pIn, (const float*)d_in[16], (const float*)d_in[17],
      (const float*)d_in[18], (const float*)d_in[19], 3);
  if (haveP) {
    p_gemm<<<dim3(4 * NGRAPH), dim3(256), 0, stream>>>(
        cs, (const float*)d_in[20], Pbuf);
    walk_head5<<<dim3(NGRAPH), dim3(256), 0, stream>>>(
        cs, Pbuf, gOut, pOut, gSE, (const float*)d_in[21],
        (const float*)d_in[22], (const float*)d_in[23], (const float*)d_in[24],
        (const float*)d_in[25], (float*)d_out);
  } else {
    walk_head4<<<dim3(NGRAPH), dim3(256), 0, stream>>>(
        cs, gOut, pOut, gSE, (const float*)d_in[20], (const float*)d_in[21],
        (const float*)d_in[22], (const float*)d_in[23], (const float*)d_in[24],
        (const float*)d_in[25], (float*)d_out);
  }
}

// Round 13
// 167.645 us; speedup vs baseline: 7.7003x; 7.7003x over previous
//
#include <hip/hip_runtime.h>
#include <math.h>

#define NGRAPH 128
#define NPER   512
#define EPER   8192
#define NFEAT  4
#define NREL   5
#define DD     128
#define MAXNB  50
#define MAXW   21
#define NCLS   5

typedef unsigned short ushortT;
typedef unsigned char ucharT;

// ===================== Kernel A: build sorted in/out CSRs (proven r3-r11) =====================
#define NTA 1024

__device__ __forceinline__ void scanExcl(const int* cnt, int* offs, int* tA,
                                         int* tB, int tid) {
  if (tid < NPER) tA[tid] = cnt[tid];
  __syncthreads();
  int* a = tA; int* b = tB;
  for (int d = 1; d < NPER; d <<= 1) {
    if (tid < NPER) {
      int v = a[tid];
      if (tid >= d) v += a[tid - d];
      b[tid] = v;
    }
    __syncthreads();
    int* t = a; a = b; b = t;
  }
  if (tid < NPER) offs[tid] = a[tid] - cnt[tid];
  __syncthreads();
}

__global__ __launch_bounds__(NTA, 1)
void build_csr2(const int* __restrict__ esrc, const int* __restrict__ edst,
                const int* __restrict__ etype, const float* __restrict__ x,
                ushortT* __restrict__ gBin, ushortT* __restrict__ gOut,
                int* __restrict__ pIn, int* __restrict__ pOut,
                int* __restrict__ gSE) {
  __shared__ int keyS[EPER];
  __shared__ int auxS[EPER];
  __shared__ ushortT nodS[EPER];
  __shared__ ucharT etyS[EPER];
  __shared__ int cnt[NPER], offs[NPER], fill[NPER];
  __shared__ int se[2];
  const int bid = blockIdx.x, tid = threadIdx.x;
  const int half = bid >> 7;             // 0: in-CSR, 1: out-CSR
  const int g = bid & 127;
  const int nbase = g * NPER, ebase = g * EPER;

  if (tid < NPER) { cnt[tid] = 0; fill[tid] = 0; }
  if (tid < 2) se[tid] = NPER;
  __syncthreads();

  if (half == 0) {
    for (int e = tid; e < EPER; e += NTA) {
      auxS[e] = esrc[ebase + e] - nbase;
      etyS[e] = (ucharT)etype[ebase + e];
      int d = edst[ebase + e] - nbase;
      atomicAdd(&cnt[d], 1);
    }
    __syncthreads();
    scanExcl(cnt, offs, keyS, keyS + NPER, tid);
    for (int e = tid; e < EPER; e += NTA) {
      int d = edst[ebase + e] - nbase;
      int pos = offs[d] + atomicAdd(&fill[d], 1);
      keyS[pos] = (d << 13) | e;
    }
    __syncthreads();
    for (int p = tid; p < EPER; p += NTA) {
      const int k = keyS[p];
      const int n = k >> 13;
      const int o = offs[n], c = cnt[n];
      int r = 0;
      for (int i = 0; i < c; ++i) r += (keyS[o + i] < k);
      const int e = k & (EPER - 1);
      gBin[(size_t)g * EPER + o + r] = (ushortT)((auxS[e] << 3) | (int)etyS[e]);
    }
    if (tid < NPER) pIn[nbase + tid] = (offs[tid] << 14) | cnt[tid];
  } else {
    for (int e = tid; e < EPER; e += NTA) {
      int s = esrc[ebase + e] - nbase;
      auxS[e] = s;
      atomicAdd(&cnt[s], 1);
    }
    if (tid < NPER) {
      if (x[(size_t)(nbase + tid) * NFEAT + 0] > 0.5f) atomicMin(&se[0], tid);
      if (x[(size_t)(nbase + tid) * NFEAT + 1] > 0.5f) atomicMin(&se[1], tid);
    }
    __syncthreads();
    scanExcl(cnt, offs, keyS, keyS + NPER, tid);
    for (int e = tid; e < EPER; e += NTA) {
      int s = auxS[e];
      int d = edst[ebase + e] - nbase;
      int pos = offs[s] + atomicAdd(&fill[s], 1);
      keyS[pos] = (d << 13) | e;
      nodS[pos] = (ushortT)s;
    }
    __syncthreads();
    for (int p = tid; p < EPER; p += NTA) {
      const int k = keyS[p];
      const int n = (int)nodS[p];
      const int o = offs[n], c = cnt[n];
      int r = 0;
      for (int i = 0; i < c; ++i) r += (keyS[o + i] < k);
      gOut[(size_t)g * EPER + o + r] = (ushortT)(k >> 13);
    }
    if (tid < NPER) pOut[nbase + tid] = (offs[tid] << 14) | cnt[tid];
    if (tid < 2) gSE[g * 2 + tid] = (se[tid] >= NPER) ? 0 : se[tid];
  }
}

// ===================== Kernel B: RGCN layer (r8 code; XCD-paired block mapping) =====================
template <int FIN>
__global__ __launch_bounds__(512, 1)
void rgcn_layer2p(const float* __restrict__ x, float* __restrict__ cs,
                  const ushortT* __restrict__ gBin, const int* __restrict__ pIn,
                  const float* __restrict__ bas, const float* __restrict__ cmp,
                  const float* __restrict__ rt, const float* __restrict__ bi,
                  int l) {
  constexpr int NK4 = (3 * FIN) / 4;
  constexpr int LPN = FIN / 4;
  __shared__ float A_s[NK4 * 256 * 4];
  __shared__ float Bt_s[NK4 * 32 * 4];
  __shared__ float compS[NREL * 2];
  const int bid = blockIdx.x, tid = threadIdx.x;
  const int g = bid & 127, half = bid >> 7;   // XCD-paired
  const int nbase = g * NPER;
  const int nb2 = nbase + half * 256;

  for (int idx = tid; idx < NK4 * 128; idx += 512) {
    const int k4 = idx >> 7, rem = idx & 127;
    const int o = rem >> 2, c = rem & 3;
    const int k = k4 * 4 + c;
    float v;
    if (k < 2 * FIN) v = bas[k * 32 + o];
    else v = rt[(k - 2 * FIN) * 32 + o];
    Bt_s[(k4 * 32 + o) * 4 + c] = v;
  }
  if (tid < NREL * 2) compS[tid] = cmp[tid];
  for (int idx = tid; idx < 256 * LPN; idx += 512) {
    const int n = idx / LPN, kq = idx % LPN;
    float4 hv;
    if constexpr (FIN == 4)
      hv = *(const float4*)(x + (size_t)(nb2 + n) * NFEAT);
    else
      hv = *(const float4*)(cs + (size_t)(nb2 + n) * DD + (l - 1) * 32 + kq * 4);
    *(float4*)&A_s[((2 * LPN + kq) * 256 + n) * 4] = hv;
  }
  __syncthreads();

  // gather with 2-deep pipeline; FMA order identical to proven kernel
  for (int t = tid; t < 256 * LPN; t += 512) {
    const int n = t / LPN, q = t % LPN;
    const int pk = pIn[nb2 + n];
    const int off = pk >> 14, c = pk & 16383;
    const float inv = 1.0f / (float)(c > 1 ? c : 1);
    float4 s0 = make_float4(0.f, 0.f, 0.f, 0.f);
    float4 s1 = make_float4(0.f, 0.f, 0.f, 0.f);
    const ushortT* el = gBin + (size_t)g * EPER + off;
    const float* hb;
    if constexpr (FIN == 4) hb = x + (size_t)nbase * NFEAT;
    else hb = cs + (size_t)nbase * DD + (l - 1) * 32 + q * 4;
    constexpr int STRIDE = (FIN == 4) ? NFEAT : DD;
    if (c > 0) {
      int pe = (int)el[0];
      float4 hv = *(const float4*)(hb + (size_t)(pe >> 3) * STRIDE);
      for (int i = 0; i + 1 < c; ++i) {
        const int pe_n = (int)el[i + 1];
        const float4 hv_n = *(const float4*)(hb + (size_t)(pe_n >> 3) * STRIDE);
        const float c0 = compS[(pe & 7) * 2], c1 = compS[(pe & 7) * 2 + 1];
        s0.x = fmaf(c0, hv.x, s0.x); s0.y = fmaf(c0, hv.y, s0.y);
        s0.z = fmaf(c0, hv.z, s0.z); s0.w = fmaf(c0, hv.w, s0.w);
        s1.x = fmaf(c1, hv.x, s1.x); s1.y = fmaf(c1, hv.y, s1.y);
        s1.z = fmaf(c1, hv.z, s1.z); s1.w = fmaf(c1, hv.w, s1.w);
        pe = pe_n; hv = hv_n;
      }
      const float c0 = compS[(pe & 7) * 2], c1 = compS[(pe & 7) * 2 + 1];
      s0.x = fmaf(c0, hv.x, s0.x); s0.y = fmaf(c0, hv.y, s0.y);
      s0.z = fmaf(c0, hv.z, s0.z); s0.w = fmaf(c0, hv.w, s0.w);
      s1.x = fmaf(c1, hv.x, s1.x); s1.y = fmaf(c1, hv.y, s1.y);
      s1.z = fmaf(c1, hv.z, s1.z); s1.w = fmaf(c1, hv.w, s1.w);
    }
    s0.x *= inv; s0.y *= inv; s0.z *= inv; s0.w *= inv;
    s1.x *= inv; s1.y *= inv; s1.z *= inv; s1.w *= inv;
    *(float4*)&A_s[(q * 256 + n) * 4] = s0;
    *(float4*)&A_s[((LPN + q) * 256 + n) * 4] = s1;
  }
  __syncthreads();

  // GEMM: thread tile 2 nodes x 8 outs (proven mapping)
  const int ot = (tid >> 4) & 3;
  const int nt = (tid & 15) | ((tid >> 6) << 4);
  const int n0 = 2 * nt, o0 = 8 * ot;
  float acc[2][8];
#pragma unroll
  for (int i = 0; i < 2; ++i)
#pragma unroll
    for (int j = 0; j < 8; ++j) acc[i][j] = 0.f;
  for (int k4 = 0; k4 < NK4; ++k4) {
    const float4 a0 = *(const float4*)&A_s[(k4 * 256 + n0) * 4];
    const float4 a1 = *(const float4*)&A_s[(k4 * 256 + n0 + 1) * 4];
#pragma unroll
    for (int j = 0; j < 8; ++j) {
      const float4 b = *(const float4*)&Bt_s[(k4 * 32 + o0 + j) * 4];
      acc[0][j] = fmaf(a0.x, b.x, acc[0][j]);
      acc[0][j] = fmaf(a0.y, b.y, acc[0][j]);
      acc[0][j] = fmaf(a0.z, b.z, acc[0][j]);
      acc[0][j] = fmaf(a0.w, b.w, acc[0][j]);
      acc[1][j] = fmaf(a1.x, b.x, acc[1][j]);
      acc[1][j] = fmaf(a1.y, b.y, acc[1][j]);
      acc[1][j] = fmaf(a1.z, b.z, acc[1][j]);
      acc[1][j] = fmaf(a1.w, b.w, acc[1][j]);
    }
  }
#pragma unroll
  for (int i = 0; i < 2; ++i) {
    float4 w0, w1;
    w0.x = tanhf(acc[i][0] + bi[o0 + 0]); w0.y = tanhf(acc[i][1] + bi[o0 + 1]);
    w0.z = tanhf(acc[i][2] + bi[o0 + 2]); w0.w = tanhf(acc[i][3] + bi[o0 + 3]);
    w1.x = tanhf(acc[i][4] + bi[o0 + 4]); w1.y = tanhf(acc[i][5] + bi[o0 + 5]);
    w1.z = tanhf(acc[i][6] + bi[o0 + 6]); w1.w = tanhf(acc[i][7] + bi[o0 + 7]);
    float* dst = cs + (size_t)(nb2 + n0 + i) * DD + l * 32 + o0;
    *(float4*)dst = w0;
    *(float4*)(dst + 4) = w1;
  }
}

// ===================== Kernel P: P[n][j] = W[j]. cs_row(n)  (verbatim r11) =====================
__global__ __launch_bounds__(256, 1)
void p_gemm(const float* __restrict__ cs, const float* __restrict__ walk_w,
            float* __restrict__ P) {
  __shared__ float A_s[32 * 128 * 4];
  __shared__ float BtS[32 * 64 * 4];
  const int bid = blockIdx.x, tid = threadIdx.x;
  const int g = bid & 127, quad = bid >> 7;
  const int nb2 = g * NPER + quad * 128;

  for (int idx = tid; idx < 64 * 32; idx += 256) {
    const int j = idx >> 5, k4 = idx & 31;
    float4 v = make_float4(0.f, 0.f, 0.f, 0.f);
    if (j < MAXNB) v = *(const float4*)(walk_w + j * DD + k4 * 4);
    *(float4*)&BtS[(k4 * 64 + j) * 4] = v;
  }
  for (int idx = tid; idx < 128 * 32; idx += 256) {
    const int n = idx >> 5, k4 = idx & 31;
    const float4 v = *(const float4*)(cs + (size_t)(nb2 + n) * DD + k4 * 4);
    *(float4*)&A_s[(k4 * 128 + n) * 4] = v;
  }
  __syncthreads();

  const int nt = tid & 31, jt = tid >> 5;
  const int n0 = 4 * nt, j0 = 8 * jt;
  float acc[4][8];
#pragma unroll
  for (int i = 0; i < 4; ++i)
#pragma unroll
    for (int j = 0; j < 8; ++j) acc[i][j] = 0.f;
  for (int k4 = 0; k4 < 32; ++k4) {
    const float4 a0 = *(const float4*)&A_s[(k4 * 128 + n0 + 0) * 4];
    const float4 a1 = *(const float4*)&A_s[(k4 * 128 + n0 + 1) * 4];
    const float4 a2 = *(const float4*)&A_s[(k4 * 128 + n0 + 2) * 4];
    const float4 a3 = *(const float4*)&A_s[(k4 * 128 + n0 + 3) * 4];
#pragma unroll
    for (int j = 0; j < 8; ++j) {
      const float4 b = *(const float4*)&BtS[(k4 * 64 + j0 + j) * 4];
      acc[0][j] = fmaf(a0.x, b.x, acc[0][j]); acc[0][j] = fmaf(a0.y, b.y, acc[0][j]);
      acc[0][j] = fmaf(a0.z, b.z, acc[0][j]); acc[0][j] = fmaf(a0.w, b.w, acc[0][j]);
      acc[1][j] = fmaf(a1.x, b.x, acc[1][j]); acc[1][j] = fmaf(a1.y, b.y, acc[1][j]);
      acc[1][j] = fmaf(a1.z, b.z, acc[1][j]); acc[1][j] = fmaf(a1.w, b.w, acc[1][j]);
      acc[2][j] = fmaf(a2.x, b.x, acc[2][j]); acc[2][j] = fmaf(a2.y, b.y, acc[2][j]);
      acc[2][j] = fmaf(a2.z, b.z, acc[2][j]); acc[2][j] = fmaf(a2.w, b.w, acc[2][j]);
      acc[3][j] = fmaf(a3.x, b.x, acc[3][j]); acc[3][j] = fmaf(a3.y, b.y, acc[3][j]);
      acc[3][j] = fmaf(a3.z, b.z, acc[3][j]); acc[3][j] = fmaf(a3.w, b.w, acc[3][j]);
    }
  }
#pragma unroll
  for (int i = 0; i < 4; ++i) {
    float4 w0, w1;
    w0.x = acc[i][0]; w0.y = acc[i][1]; w0.z = acc[i][2]; w0.w = acc[i][3];
    w1.x = acc[i][4]; w1.y = acc[i][5]; w1.z = acc[i][6]; w1.w = acc[i][7];
    float* dst = P + (size_t)(nb2 + n0 + i) * 64 + j0;
    *(float4*)dst = w0;
    *(float4*)(dst + 4) = w1;
  }
}

// ===================== Kernel C: P-based walk + MLP head (verbatim r11) =====================
__global__ __launch_bounds__(256, 1)
void walk_head5(const float* __restrict__ cs, const float* __restrict__ P,
                const ushortT* __restrict__ gOut, const int* __restrict__ pOut,
                const int* __restrict__ gSE, const float* __restrict__ walk_b,
                const float* __restrict__ lin1_w, const float* __restrict__ lin1_b,
                const float* __restrict__ lin2_w, const float* __restrict__ lin2_b,
                float* __restrict__ out) {
  __shared__ ushortT gOutS[EPER];
  __shared__ int pOutS[NPER];
  __shared__ int travS[NPER];
  __shared__ int listS[MAXW + 2];
  __shared__ int scal[4];
  __shared__ float pooledS[DD], hidS[DD], logitsS[8];
  const int g = blockIdx.x, tid = threadIdx.x;
  const int nbase = g * NPER;
  const float* Pg = P + (size_t)nbase * 64;

  {
    const unsigned int* g32 = (const unsigned int*)(gOut + (size_t)g * EPER);
    unsigned int* s32 = (unsigned int*)gOutS;
    for (int i = tid; i < EPER / 2; i += 256) s32[i] = g32[i];
    for (int i = tid; i < NPER; i += 256) {
      pOutS[i] = pOut[nbase + i];
      travS[i] = 0;
    }
  }
  const int startN = gSE[2 * g];
  const int endN = gSE[2 * g + 1];
  if (tid == 0) { travS[startN] = 1; listS[0] = startN; }
  __syncthreads();

  if (tid < 64) {
    const int j = tid;
    float l = 0.f;
    if (j < MAXNB) l = Pg[(size_t)startN * 64 + j] + walk_b[j];
    int node = startN, visited = 1, nrows = 1;
    for (int step = 0; step < MAXW; ++step) {
      const int pk = pOutS[node];
      const int off = pk >> 14, c = pk & 16383;
      const int jm = (c < MAXNB) ? c : MAXNB;
      float myval = -INFINITY;
      if (j < jm) {
        const int nb = (int)gOutS[off + j];
        if (!travS[nb]) myval = l;
      }
      int myidx = j;
#pragma unroll
      for (int o = 1; o < 64; o <<= 1) {
        const float ov = __shfl_xor(myval, o, 64);
        const int oi = __shfl_xor(myidx, o, 64);
        if (ov > myval || (ov == myval && oi < myidx)) { myval = ov; myidx = oi; }
      }
      const bool no_nbr = (c == 0);
      const int sel = no_nbr ? 0 : (int)gOutS[off + myidx];
      const int tgt = no_nbr ? endN : sel;
      if (j == 0) listS[nrows] = tgt;
      nrows++;
      if (j < MAXNB) l += Pg[(size_t)tgt * 64 + j];
      if (!no_nbr) {
        if (j == 0) travS[sel] = 1;
        visited++;
        node = sel;
      }
      if (no_nbr || sel == endN) break;
    }
    if (j == 0) { scal[0] = nrows; scal[1] = visited; }
  }
  __syncthreads();

  const int nrows = scal[0];
  if (tid < DD) {
    float acc = cs[(size_t)(nbase + listS[0]) * DD + tid];
    for (int t = 1; t < nrows; ++t)
      acc += cs[(size_t)(nbase + listS[t]) * DD + tid];
    pooledS[tid] = acc / (float)scal[1];
  }
  __syncthreads();
  if (tid < DD) {
    const float4* w4 = (const float4*)(lin1_w + (size_t)tid * DD);
    float s = lin1_b[tid];
#pragma unroll 8
    for (int k4 = 0; k4 < DD / 4; ++k4) {
      const float4 wv = w4[k4];
      s += wv.x * pooledS[k4 * 4 + 0] + wv.y * pooledS[k4 * 4 + 1]
         + wv.z * pooledS[k4 * 4 + 2] + wv.w * pooledS[k4 * 4 + 3];
    }
    hidS[tid] = fmaxf(s, 0.f);
  }
  __syncthreads();
  if (tid < NCLS) {
    const float4* w4 = (const float4*)(lin2_w + (size_t)tid * DD);
    float s = lin2_b[tid];
#pragma unroll 8
    for (int k4 = 0; k4 < DD / 4; ++k4) {
      const float4 wv = w4[k4];
      s += wv.x * hidS[k4 * 4 + 0] + wv.y * hidS[k4 * 4 + 1]
         + wv.z * hidS[k4 * 4 + 2] + wv.w * hidS[k4 * 4 + 3];
    }
    logitsS[tid] = s;
  }
  __syncthreads();
  if (tid < NCLS) {
    float m = logitsS[0];
    for (int c = 1; c < NCLS; ++c) m = fmaxf(m, logitsS[c]);
    float sum = 0.f;
    for (int c = 0; c < NCLS; ++c) sum += expf(logitsS[c] - m);
    const float lse = m + logf(sum);
    out[g * NCLS + tid] = logitsS[tid] - lse;
  }
}

// ===================== Fallback walk (verbatim r9-r11, proven) =====================
__global__ __launch_bounds__(256, 1)
void walk_head4(const float* __restrict__ cs, const ushortT* __restrict__ gOut,
                const int* __restrict__ pOut, const int* __restrict__ gSE,
                const float* __restrict__ walk_w, const float* __restrict__ walk_b,
                const float* __restrict__ lin1_w, const float* __restrict__ lin1_b,
                const float* __restrict__ lin2_w, const float* __restrict__ lin2_b,
                float* __restrict__ out) {
  __shared__ float wT2[64 * 136];
  __shared__ float rowS[DD];
  __shared__ ushortT gOutS[EPER];
  __shared__ int pOutS[NPER];
  __shared__ int travS[NPER];
  __shared__ int listS[MAXW + 2];
  __shared__ int scal[4];
  __shared__ float pooledS[DD], hidS[DD], logitsS[8];
  const int g = blockIdx.x, tid = threadIdx.x;
  const int nbase = g * NPER;

  for (int i = tid; i < 64 * 128; i += 256) {
    const int j = i >> 7, k = i & 127;
    wT2[j * 136 + k] = (j < MAXNB) ? walk_w[j * DD + k] : 0.f;
  }
  {
    const unsigned int* g32 = (const unsigned int*)(gOut + (size_t)g * EPER);
    unsigned int* s32 = (unsigned int*)gOutS;
    for (int i = tid; i < EPER / 2; i += 256) s32[i] = g32[i];
    for (int i = tid; i < NPER; i += 256) {
      pOutS[i] = pOut[nbase + i];
      travS[i] = 0;
    }
  }
  const int startN = gSE[2 * g];
  const int endN = gSE[2 * g + 1];
  if (tid < 64)
    ((float2*)rowS)[tid] = ((const float2*)(cs + (size_t)(nbase + startN) * DD))[tid];
  if (tid == 0) { travS[startN] = 1; listS[0] = startN; }
  __syncthreads();

  if (tid < 64) {
    const int j = tid;
    const float* wrow = wT2 + j * 136;
    float l = (j < MAXNB) ? walk_b[j] : 0.f;
#pragma unroll
    for (int k4 = 0; k4 < 32; ++k4) {
      const float4 r = *(const float4*)&rowS[k4 * 4];
      const float4 w = *(const float4*)&wrow[k4 * 4];
      l = fmaf(w.w, r.w, fmaf(w.z, r.z, fmaf(w.y, r.y, fmaf(w.x, r.x, l))));
    }
    int node = startN, visited = 1, nrows = 1;
    for (int step = 0; step < MAXW; ++step) {
      const int pk = pOutS[node];
      const int off = pk >> 14, c = pk & 16383;
      const int jm = (c < MAXNB) ? c : MAXNB;
      float myval = -INFINITY;
      if (j < jm) {
        const int nb = (int)gOutS[off + j];
        if (!travS[nb]) myval = l;
      }
      int myidx = j;
#pragma unroll
      for (int o = 1; o < 64; o <<= 1) {
        const float ov = __shfl_xor(myval, o, 64);
        const int oi = __shfl_xor(myidx, o, 64);
        if (ov > myval || (ov == myval && oi < myidx)) { myval = ov; myidx = oi; }
      }
      const bool no_nbr = (c == 0);
      const int sel = no_nbr ? 0 : (int)gOutS[off + myidx];
      const int tgt = no_nbr ? endN : sel;
      if (j == 0) listS[nrows] = tgt;
      nrows++;
      const float2 rv = ((const float2*)(cs + (size_t)(nbase + tgt) * DD))[j];
      ((float2*)rowS)[j] = rv;
#pragma unroll
      for (int k4 = 0; k4 < 32; ++k4) {
        const float4 r = *(const float4*)&rowS[k4 * 4];
        const float4 w = *(const float4*)&wrow[k4 * 4];
        l = fmaf(w.w, r.w, fmaf(w.z, r.z, fmaf(w.y, r.y, fmaf(w.x, r.x, l))));
      }
      if (!no_nbr) {
        if (j == 0) travS[sel] = 1;
        visited++;
        node = sel;
      }
      if (no_nbr || sel == endN) break;
    }
    if (j == 0) { scal[0] = nrows; scal[1] = visited; }
  }
  __syncthreads();

  const int nrows = scal[0];
  if (tid < DD) {
    float acc = cs[(size_t)(nbase + listS[0]) * DD + tid];
    for (int t = 1; t < nrows; ++t)
      acc += cs[(size_t)(nbase + listS[t]) * DD + tid];
    pooledS[tid] = acc / (float)scal[1];
  }
  __syncthreads();
  if (tid < DD) {
    const float4* w4 = (const float4*)(lin1_w + (size_t)tid * DD);
    float s = lin1_b[tid];
#pragma unroll 8
    for (int k4 = 0; k4 < DD / 4; ++k4) {
      const float4 wv = w4[k4];
      s += wv.x * pooledS[k4 * 4 + 0] + wv.y * pooledS[k4 * 4 + 1]
         + wv.z * pooledS[k4 * 4 + 2] + wv.w * pooledS[k4 * 4 + 3];
    }
    hidS[tid] = fmaxf(s, 0.f);
  }
  __syncthreads();
  if (tid < NCLS) {
    const float4* w4 = (const float4*)(lin2_w + (size_t)tid * DD);
    float s = lin2_b[tid];
#pragma unroll 8
    for (int k4 = 0; k4 < DD / 4; ++k4) {
      const float4 wv = w4[k4];
      s += wv.x * hidS[k4 * 4 + 0] + wv.y * hidS[k4 * 4 + 1]
         + wv.z * hidS[k4 * 4 + 2] + wv.w * hidS[k4 * 4 + 3];
    }
    logitsS[tid] = s;
  }
  __syncthreads();
  if (tid < NCLS) {
    float m = logitsS[0];
    for (int c = 1; c < NCLS; ++c) m = fmaxf(m, logitsS[c]);
    float sum = 0.f;
    for (int c = 0; c < NCLS; ++c) sum += expf(logitsS[c] - m);
    const float lse = m + logf(sum);
    out[g * NCLS + tid] = logitsS[tid] - lse;
  }
}

extern "C" void kernel_launch(void* const* d_in, const int* in_sizes, int n_in,
                              void* d_out, int out_size, void* d_ws, size_t ws_size,
                              hipStream_t stream) {
  const float* x = (const float*)d_in[0];
  const int* ei = (const int*)d_in[1];
  const int E = in_sizes[1] / 2;
  const int* esrc = ei;
  const int* edst = ei + E;
  const int* et = (const int*)d_in[2];

  char* ws = (char*)d_ws;
  float* cs = (float*)ws;
  size_t off = (size_t)NGRAPH * NPER * DD * sizeof(float);
  ushortT* gBin = (ushortT*)(ws + off); off += (size_t)NGRAPH * EPER * sizeof(ushortT);
  ushortT* gOut = (ushortT*)(ws + off); off += (size_t)NGRAPH * EPER * sizeof(ushortT);
  int* pIn = (int*)(ws + off); off += (size_t)NGRAPH * NPER * sizeof(int);
  int* pOut = (int*)(ws + off); off += (size_t)NGRAPH * NPER * sizeof(int);
  int* gSE = (int*)(ws + off); off += (size_t)NGRAPH * 2 * sizeof(int);
  off = (off + 255) & ~(size_t)255;
  float* Pbuf = (float*)(ws + off);
  const size_t pBytes = (size_t)NGRAPH * NPER * 64 * sizeof(float);
  const bool haveP = (ws_size >= off + pBytes);

  build_csr2<<<dim3(2 * NGRAPH), dim3(NTA), 0, stream>>>(esrc, edst, et, x, gBin,
                                                         gOut, pIn, pOut, gSE);
  rgcn_layer2p<NFEAT><<<dim3(2 * NGRAPH), dim3(512), 0, stream>>>(
      x, cs, gBin, pIn, (const float*)d_in[4], (const float*)d_in[5],
      (const float*)d_in[6], (const float*)d_in[7], 0);
  rgcn_layer2p<32><<<dim3(2 * NGRAPH), dim3(512), 0, stream>>>(
      x, cs, gBin, pIn, (const float*)d_in[8], (const float*)d_in[9],
      (const float*)d_in[10], (const float*)d_in[11], 1);
  rgcn_layer2p<32><<<dim3(2 * NGRAPH), dim3(512), 0, stream>>>(
      x, cs, gBin, pIn, (const float*)d_in[12], (const float*)d_in[13],
      (const float*)d_in[14], (const float*)d_in[15], 2);
  rgcn_layer2p<32><<<dim3(2 * NGRAPH), dim3(512), 0, stream>>>(
      x, cs, gBin, pIn, (const float*)d_in[16], (const float*)d_in[17],
      (const float*)d_in[18], (const float*)d_in[19], 3);
  if (haveP) {
    p_gemm<<<dim3(4 * NGRAPH), dim3(256), 0, stream>>>(
        cs, (const float*)d_in[20], Pbuf);
    walk_head5<<<dim3(NGRAPH), dim3(256), 0, stream>>>(
        cs, Pbuf, gOut, pOut, gSE, (const float*)d_in[21],
        (const float*)d_in[22], (const float*)d_in[23], (const float*)d_in[24],
        (const float*)d_in[25], (float*)d_out);
  } else {
    walk_head4<<<dim3(NGRAPH), dim3(256), 0, stream>>>(
        cs, gOut, pOut, gSE, (const float*)d_in[20], (const float*)d_in[21],
        (const float*)d_in[22], (const float*)d_in[23], (const float*)d_in[24],
        (const float*)d_in[25], (float*)d_out);
  }
}